// Round 17
// baseline (299.984 us; speedup 1.0000x reference)
//
#include <hip/hip_runtime.h>
#include <cstdint>

namespace {

typedef _Float16 half2v __attribute__((ext_vector_type(2)));
typedef _Float16 half8 __attribute__((ext_vector_type(8)));
typedef float f32x4 __attribute__((ext_vector_type(4)));
typedef unsigned int u32x4 __attribute__((ext_vector_type(4)));

constexpr int KFS = 51;
constexpr int NB = 2, NC = 3, HH = 512, WW = 512;
constexpr int HP = HH + KFS - 1;   // 562
constexpr int WP = WW + KFS - 1;   // 562
constexpr size_t VSTR = (size_t)HH * WW;

constexpr int XCH = 32;            // output cols per block
constexpr int SP = 4;              // phases per block
constexpr int YSTRIP = 32;         // output rows per block (8 per phase)
constexpr int NTHREADS = 512;      // 8 waves; wave w owns row (phase*8 + w)
constexpr int NRB = 80;            // rolling A row slots
constexpr int NPL = NC * 3 * 4;    // 36 (c,ks,lq) planes
constexpr int ASZ = NPL * NRB * 4; // 11520 dw = 46.1 KB
constexpr int AV0 = NPL * 71;      // 2556 phase-0 stage units
constexpr int SS = 26;             // f16-pair slots (taps 0..51)
constexpr int SLROW = 28;          // + zero guards at slot 0 and 27
constexpr int SLSZ = 8 * SLROW * 32;  // 7168 dw = 28.7 KB

__device__ __forceinline__ uint32_t pack2(float a, float b) {
  half2v p;
  p.x = (_Float16)a;  // RNE
  p.y = (_Float16)b;
  return __builtin_bit_cast(uint32_t, p);
}

__global__ __launch_bounds__(NTHREADS, 4)
void sepconv_mfma(const float* __restrict__ in1, const float* __restrict__ in2,
                  const float* __restrict__ in3, float* __restrict__ out) {
  __shared__ __align__(16) uint32_t ALDS[ASZ];  // A[c][ks][lq][slot][4dw], rolling
  __shared__ uint32_t SLAB[SLSZ];               // per-wave h-pair rows

  const int t = threadIdx.x;
  const int lane = t & 63;
  const int w = t >> 6;
  const int l15 = lane & 15;
  const int lq = lane >> 4;
  const int sn = lane & 31;
  const int shf = lane >> 5;
  const int sh = (l15 & 1) * 16;

  const int x0 = blockIdx.x * XCH;
  const int ys0 = blockIdx.y * YSTRIP;
  const int b = blockIdx.z;

  const float* in1b = in1 + (size_t)b * NC * HP * WP;
  const float* v2 = in2 + (size_t)b * KFS * VSTR;
  const float* h3 = in3 + (size_t)b * KFS * VSTR;
  uint32_t* SLW = &SLAB[w * SLROW * 32];

  // ---- prologue: A rows 0..70 (batched 2x10) -------------------------------
  {
    const int e2 = t & 3;
    int v = t >> 2;
    int ww2 = (v >= 71) ? 1 : 0;
    int r = v - ww2 * 71;
    float2 ga[10];
    #pragma unroll
    for (int half = 0; half < 2; ++half) {
      int vs = v, rs = r, ws = ww2;
      #pragma unroll
      for (int s = 0; s < 10; ++s) {
        float2 g = make_float2(0.f, 0.f);
        if (vs < AV0) {
          const int lqi = ws & 3;
          const int cks = ws >> 2;
          const int c = cks / 3;
          const int ks = cks - 3 * c;
          const int k0 = ks * 32 + lqi * 8 + 2 * e2;
          const int row = min(ys0 + rs, HP - 1);
          if (k0 < 82)
            g = *reinterpret_cast<const float2*>(
                in1b + ((size_t)c * HP + row) * WP + x0 + k0);
        }
        ga[s] = g;
        vs += 128; rs += 57; ws += 1;
        if (rs >= 71) { rs -= 71; ++ws; }
      }
      int vs2 = v, rs2 = r, ws2 = ww2;
      #pragma unroll
      for (int s = 0; s < 10; ++s) {
        if (vs2 < AV0) ALDS[((ws2 * NRB + rs2) << 2) | e2] = pack2(ga[s].x, ga[s].y);
        vs2 += 128; rs2 += 57; ws2 += 1;
        if (rs2 >= 71) { rs2 -= 71; ++ws2; }
      }
      v = vs; r = rs; ww2 = ws;
    }
  }
  // ---- prologue: wave-local slab for y = ys0 + w ---------------------------
  {
    const float* hp = h3 + (size_t)(ys0 + w) * WW + x0 + sn;
    float sa[13], sb[13];
    #pragma unroll
    for (int i = 0; i < 13; ++i) {
      const int s = 2 * i + shf;
      sa[i] = hp[(size_t)(2 * s) * VSTR];
      sb[i] = (2 * s + 1 < KFS) ? hp[(size_t)(2 * s + 1) * VSTR] : 0.f;
    }
    SLW[(shf ? (SLROW - 1) : 0) * 32 + sn] = 0u;  // zero guards (persist)
    #pragma unroll
    for (int i = 0; i < 13; ++i)
      SLW[(2 * i + shf + 1) * 32 + sn] = pack2(sa[i], sb[i]);
  }
  __syncthreads();

  // ---- phases --------------------------------------------------------------
  #pragma unroll 1
  for (int p = 0; p < SP; ++p) {
    const int yp = ys0 + 8 * p + w;
    const int rbase = 8 * p + w;
    const bool more = (p + 1 < SP);

    // B fragments from SLW (current y's slab)
    u32x4 bf[2][3];
    #pragma unroll
    for (int nt = 0; nt < 2; ++nt) {
      const int n = nt * 16 + l15;
      #pragma unroll
      for (int ks = 0; ks < 3; ++ks) {
        const int sB = (ks * 32 + lq * 8 - n) >> 1;
        uint32_t P[5];
        #pragma unroll
        for (int u = 0; u < 5; ++u) {
          const int sc = min(max(sB + u, -1), SS) + 1;  // 0..27; 0 & 27 zero
          P[u] = SLW[sc * 32 + n];
        }
        u32x4 f;
        f.x = __builtin_amdgcn_alignbit(P[1], P[0], sh);
        f.y = __builtin_amdgcn_alignbit(P[2], P[1], sh);
        f.z = __builtin_amdgcn_alignbit(P[3], P[2], sh);
        f.w = __builtin_amdgcn_alignbit(P[4], P[3], sh);
        bf[nt][ks] = f;
      }
    }

    // vw loads (issued now, consumed at phase end)
    float vw[4][2][4];
    #pragma unroll
    for (int mt = 0; mt < 4; ++mt)
      #pragma unroll
      for (int nt = 0; nt < 2; ++nt)
        #pragma unroll
        for (int r = 0; r < 4; ++r) {
          const int m = mt * 16 + lq * 4 + r;
          vw[mt][nt][r] = (m < KFS)
              ? v2[(size_t)m * VSTR + (size_t)yp * WW + x0 + nt * 16 + l15] : 0.f;
        }

    // T14 issue-early: next-phase slab (26) + A-delta (<=3 float2)
    float sa[13], sb[13];
    if (more) {
      const float* hp = h3 + (size_t)(yp + 8) * WW + x0 + sn;
      #pragma unroll
      for (int i = 0; i < 13; ++i) {
        const int s = 2 * i + shf;
        sa[i] = hp[(size_t)(2 * s) * VSTR];
        sb[i] = (2 * s + 1 < KFS) ? hp[(size_t)(2 * s + 1) * VSTR] : 0.f;
      }
    }
    float2 gd[3];
    int du[3];
    #pragma unroll
    for (int s = 0; s < 3; ++s) {
      du[s] = -1;
      if (more) {
        const int u = t + s * NTHREADS;
        if (u < 1152) {
          const int kp = u % 48;
          const int dr = (u / 48) & 7;
          const int c = u / 384;
          const int rg = 71 + 8 * p + dr;
          const int row = min(ys0 + rg, HP - 1);
          float2 g = make_float2(0.f, 0.f);
          if (kp < 41)
            g = *reinterpret_cast<const float2*>(
                in1b + ((size_t)c * HP + row) * WP + x0 + 2 * kp);
          gd[s] = g;
          int slot = rg;
          if (slot >= NRB) slot -= NRB;
          du[s] = ((((c * 3 + (kp >> 4)) * 4 + ((kp >> 2) & 3)) * NRB + slot) << 2) | (kp & 3);
        }
      }
    }

    // main MFMA loop
    float ps[2][NC] = {};
    #pragma unroll
    for (int mt = 0; mt < 4; ++mt) {
      int sl = rbase + mt * 16 + l15;
      if (sl >= NRB) sl -= NRB;
      #pragma unroll
      for (int c = 0; c < NC; ++c) {
        u32x4 af[3];
        #pragma unroll
        for (int ks = 0; ks < 3; ++ks)
          af[ks] = *reinterpret_cast<const u32x4*>(
              &ALDS[((((c * 3 + ks) * 4 + lq) * NRB + sl) << 2)]);
        #pragma unroll
        for (int nt = 0; nt < 2; ++nt) {
          f32x4 acc = {0.f, 0.f, 0.f, 0.f};
          #pragma unroll
          for (int ks = 0; ks < 3; ++ks)
            acc = __builtin_amdgcn_mfma_f32_16x16x32_f16(
                __builtin_bit_cast(half8, af[ks]),
                __builtin_bit_cast(half8, bf[nt][ks]), acc, 0, 0, 0);
          float q = acc[0] * vw[mt][nt][0];
          q = fmaf(acc[1], vw[mt][nt][1], q);
          q = fmaf(acc[2], vw[mt][nt][2], q);
          q = fmaf(acc[3], vw[mt][nt][3], q);
          ps[nt][c] += q;
        }
      }
    }

    // wave-local m-reduce + merged 32-lane store
    #pragma unroll
    for (int c = 0; c < NC; ++c) {
      float pa = ps[0][c];
      pa += __shfl_xor(pa, 16);
      pa += __shfl_xor(pa, 32);
      float pb = ps[1][c];
      pb += __shfl_xor(pb, 16);
      pb += __shfl_xor(pb, 32);
      const float po = (lane < 16) ? pa : pb;
      if (lane < 32)
        out[((size_t)(b * NC + c) * HH + yp) * WW + x0 + lane] = po;
    }

    // T14 write-late: slab(y+8) into SLW (after B-build reads; in-order DS),
    // A-delta into rolling slots (disjoint from this phase's reads).
    if (more) {
      #pragma unroll
      for (int i = 0; i < 13; ++i)
        SLW[(2 * i + shf + 1) * 32 + sn] = pack2(sa[i], sb[i]);
      #pragma unroll
      for (int s = 0; s < 3; ++s)
        if (du[s] >= 0) ALDS[du[s]] = pack2(gd[s].x, gd[s].y);
    }
    __syncthreads();
  }
}

}  // namespace

extern "C" void kernel_launch(void* const* d_in, const int* in_sizes, int n_in,
                              void* d_out, int out_size, void* d_ws, size_t ws_size,
                              hipStream_t stream) {
  const float* in1 = (const float*)d_in[0];
  const float* in2 = (const float*)d_in[1];
  const float* in3 = (const float*)d_in[2];
  float* out = (float*)d_out;

  dim3 grid(WW / XCH, HH / YSTRIP, NB);
  sepconv_mfma<<<grid, NTHREADS, 0, stream>>>(in1, in2, in3, out);
}

// Round 18
// 72.535 us; speedup vs baseline: 4.1357x; 4.1357x over previous
//
#include <hip/hip_runtime.h>
#include <cstdint>

namespace {

typedef _Float16 half2v __attribute__((ext_vector_type(2)));
typedef _Float16 half8 __attribute__((ext_vector_type(8)));
typedef float f32x4 __attribute__((ext_vector_type(4)));
typedef unsigned int u32x4 __attribute__((ext_vector_type(4)));

constexpr int KFS = 51;
constexpr int NB = 2, NC = 3, HH = 512, WW = 512;
constexpr int HP = HH + KFS - 1;   // 562
constexpr int WP = WW + KFS - 1;   // 562
constexpr size_t VSTR = (size_t)HH * WW;

constexpr int XCH = 32;            // output cols per block
constexpr int SP = 4;              // phases per block
constexpr int YSTRIP = 32;         // output rows per block (8 per phase)
constexpr int NTHREADS = 512;      // 8 waves; wave w owns row (phase*8 + w)
constexpr int NRB = 80;            // rolling A row slots
constexpr int NPL = NC * 3 * 4;    // 36 (c,ks,lq) planes
constexpr int ASZ = NPL * NRB * 4; // 11520 dw = 46.1 KB
constexpr int AV0 = NPL * 71;      // 2556 phase-0 stage units
constexpr int SS = 26;             // f16-pair slots (taps 0..51)
constexpr int SLROW = 28;          // + zero guards at slot 0 and 27
constexpr int SLSZ = 8 * SLROW * 32;  // 7168 dw = 28.7 KB

__device__ __forceinline__ uint32_t pack2(float a, float b) {
  half2v p;
  p.x = (_Float16)a;  // RNE
  p.y = (_Float16)b;
  return __builtin_bit_cast(uint32_t, p);
}

__global__ __launch_bounds__(NTHREADS, 2)
void sepconv_mfma(const float* __restrict__ in1, const float* __restrict__ in2,
                  const float* __restrict__ in3, float* __restrict__ out) {
  __shared__ __align__(16) uint32_t ALDS[ASZ];  // A[c][ks][lq][slot][4dw], rolling
  __shared__ uint32_t SLAB[SLSZ];               // per-wave h-pair rows

  const int t = threadIdx.x;
  const int lane = t & 63;
  const int w = t >> 6;
  const int l15 = lane & 15;
  const int lq = lane >> 4;
  const int sn = lane & 31;
  const int shf = lane >> 5;
  const int sh = (l15 & 1) * 16;

  const int x0 = blockIdx.x * XCH;
  const int ys0 = blockIdx.y * YSTRIP;
  const int b = blockIdx.z;

  const float* in1b = in1 + (size_t)b * NC * HP * WP;
  const float* v2 = in2 + (size_t)b * KFS * VSTR;
  const float* h3 = in3 + (size_t)b * KFS * VSTR;
  uint32_t* SLW = &SLAB[w * SLROW * 32];

  // ---- prologue: A rows 0..70 (batched 2x10) -------------------------------
  {
    const int e2 = t & 3;
    int v = t >> 2;
    int ww2 = (v >= 71) ? 1 : 0;
    int r = v - ww2 * 71;
    float2 ga[10];
    #pragma unroll
    for (int half = 0; half < 2; ++half) {
      int vs = v, rs = r, ws = ww2;
      #pragma unroll
      for (int s = 0; s < 10; ++s) {
        float2 g = make_float2(0.f, 0.f);
        if (vs < AV0) {
          const int lqi = ws & 3;
          const int cks = ws >> 2;
          const int c = cks / 3;
          const int ks = cks - 3 * c;
          const int k0 = ks * 32 + lqi * 8 + 2 * e2;
          const int row = min(ys0 + rs, HP - 1);
          if (k0 < 82)
            g = *reinterpret_cast<const float2*>(
                in1b + ((size_t)c * HP + row) * WP + x0 + k0);
        }
        ga[s] = g;
        vs += 128; rs += 57; ws += 1;
        if (rs >= 71) { rs -= 71; ++ws; }
      }
      int vs2 = v, rs2 = r, ws2 = ww2;
      #pragma unroll
      for (int s = 0; s < 10; ++s) {
        if (vs2 < AV0) ALDS[((ws2 * NRB + rs2) << 2) | e2] = pack2(ga[s].x, ga[s].y);
        vs2 += 128; rs2 += 57; ws2 += 1;
        if (rs2 >= 71) { rs2 -= 71; ++ws2; }
      }
      v = vs; r = rs; ww2 = ws;
    }
  }
  // ---- prologue: wave-local slab for y = ys0 + w ---------------------------
  {
    const float* hp = h3 + (size_t)(ys0 + w) * WW + x0 + sn;
    float sa[13], sb[13];
    #pragma unroll
    for (int i = 0; i < 13; ++i) {
      const int s = 2 * i + shf;
      sa[i] = hp[(size_t)(2 * s) * VSTR];
      sb[i] = (2 * s + 1 < KFS) ? hp[(size_t)(2 * s + 1) * VSTR] : 0.f;
    }
    SLW[(shf ? (SLROW - 1) : 0) * 32 + sn] = 0u;  // zero guards (persist)
    #pragma unroll
    for (int i = 0; i < 13; ++i)
      SLW[(2 * i + shf + 1) * 32 + sn] = pack2(sa[i], sb[i]);
  }
  __syncthreads();

  // ---- phases --------------------------------------------------------------
  #pragma unroll 1
  for (int p = 0; p < SP; ++p) {
    const int yp = ys0 + 8 * p + w;
    const int rbase = 8 * p + w;
    const bool more = (p + 1 < SP);

    // B fragments from SLW (current y's slab)
    u32x4 bf[2][3];
    #pragma unroll
    for (int nt = 0; nt < 2; ++nt) {
      const int n = nt * 16 + l15;
      #pragma unroll
      for (int ks = 0; ks < 3; ++ks) {
        const int sB = (ks * 32 + lq * 8 - n) >> 1;
        uint32_t P[5];
        #pragma unroll
        for (int u = 0; u < 5; ++u) {
          const int sc = min(max(sB + u, -1), SS) + 1;  // 0..27; 0 & 27 zero
          P[u] = SLW[sc * 32 + n];
        }
        u32x4 f;
        f.x = __builtin_amdgcn_alignbit(P[1], P[0], sh);
        f.y = __builtin_amdgcn_alignbit(P[2], P[1], sh);
        f.z = __builtin_amdgcn_alignbit(P[3], P[2], sh);
        f.w = __builtin_amdgcn_alignbit(P[4], P[3], sh);
        bf[nt][ks] = f;
      }
    }

    // T14 issue-early: next-phase slab (26) + A-delta (<=3 float2)
    float sa[13], sb[13];
    if (more) {
      const float* hp = h3 + (size_t)(yp + 8) * WW + x0 + sn;
      #pragma unroll
      for (int i = 0; i < 13; ++i) {
        const int s = 2 * i + shf;
        sa[i] = hp[(size_t)(2 * s) * VSTR];
        sb[i] = (2 * s + 1 < KFS) ? hp[(size_t)(2 * s + 1) * VSTR] : 0.f;
      }
    }
    float2 gd[3];
    int du[3];
    #pragma unroll
    for (int s = 0; s < 3; ++s) {
      du[s] = -1;
      if (more) {
        const int u = t + s * NTHREADS;
        if (u < 1152) {
          const int kp = u % 48;
          const int dr = (u / 48) & 7;
          const int c = u / 384;
          const int rg = 71 + 8 * p + dr;
          const int row = min(ys0 + rg, HP - 1);
          float2 g = make_float2(0.f, 0.f);
          if (kp < 41)
            g = *reinterpret_cast<const float2*>(
                in1b + ((size_t)c * HP + row) * WP + x0 + 2 * kp);
          gd[s] = g;
          int slot = rg;
          if (slot >= NRB) slot -= NRB;
          du[s] = ((((c * 3 + (kp >> 4)) * 4 + ((kp >> 2) & 3)) * NRB + slot) << 2) | (kp & 3);
        }
      }
    }

    // main MFMA loop; vw software-pipelined per-mt (16 live regs, not 32)
    float vwc[2][4];
    #pragma unroll
    for (int nt = 0; nt < 2; ++nt)
      #pragma unroll
      for (int r = 0; r < 4; ++r) {
        const int m = lq * 4 + r;  // mt = 0
        vwc[nt][r] = (m < KFS)
            ? v2[(size_t)m * VSTR + (size_t)yp * WW + x0 + nt * 16 + l15] : 0.f;
      }

    float ps[2][NC] = {};
    #pragma unroll
    for (int mt = 0; mt < 4; ++mt) {
      float vwn[2][4];
      if (mt < 3) {
        #pragma unroll
        for (int nt = 0; nt < 2; ++nt)
          #pragma unroll
          for (int r = 0; r < 4; ++r) {
            const int m = (mt + 1) * 16 + lq * 4 + r;
            vwn[nt][r] = (m < KFS)
                ? v2[(size_t)m * VSTR + (size_t)yp * WW + x0 + nt * 16 + l15] : 0.f;
          }
      }
      int sl = rbase + mt * 16 + l15;
      if (sl >= NRB) sl -= NRB;
      #pragma unroll
      for (int c = 0; c < NC; ++c) {
        u32x4 af[3];
        #pragma unroll
        for (int ks = 0; ks < 3; ++ks)
          af[ks] = *reinterpret_cast<const u32x4*>(
              &ALDS[((((c * 3 + ks) * 4 + lq) * NRB + sl) << 2)]);
        #pragma unroll
        for (int nt = 0; nt < 2; ++nt) {
          f32x4 acc = {0.f, 0.f, 0.f, 0.f};
          #pragma unroll
          for (int ks = 0; ks < 3; ++ks)
            acc = __builtin_amdgcn_mfma_f32_16x16x32_f16(
                __builtin_bit_cast(half8, af[ks]),
                __builtin_bit_cast(half8, bf[nt][ks]), acc, 0, 0, 0);
          float q = acc[0] * vwc[nt][0];
          q = fmaf(acc[1], vwc[nt][1], q);
          q = fmaf(acc[2], vwc[nt][2], q);
          q = fmaf(acc[3], vwc[nt][3], q);
          ps[nt][c] += q;
        }
      }
      if (mt < 3) {
        #pragma unroll
        for (int nt = 0; nt < 2; ++nt)
          #pragma unroll
          for (int r = 0; r < 4; ++r) vwc[nt][r] = vwn[nt][r];
      }
    }

    // wave-local m-reduce + merged 32-lane store
    #pragma unroll
    for (int c = 0; c < NC; ++c) {
      float pa = ps[0][c];
      pa += __shfl_xor(pa, 16);
      pa += __shfl_xor(pa, 32);
      float pb = ps[1][c];
      pb += __shfl_xor(pb, 16);
      pb += __shfl_xor(pb, 32);
      const float po = (lane < 16) ? pa : pb;
      if (lane < 32)
        out[((size_t)(b * NC + c) * HH + yp) * WW + x0 + lane] = po;
    }

    // T14 write-late: slab(y+8) into SLW (after B-build reads; in-order DS),
    // A-delta into rolling slots (disjoint from this phase's reads).
    if (more) {
      #pragma unroll
      for (int i = 0; i < 13; ++i)
        SLW[(2 * i + shf + 1) * 32 + sn] = pack2(sa[i], sb[i]);
      #pragma unroll
      for (int s = 0; s < 3; ++s)
        if (du[s] >= 0) ALDS[du[s]] = pack2(gd[s].x, gd[s].y);
    }
    __syncthreads();
  }
}

}  // namespace

extern "C" void kernel_launch(void* const* d_in, const int* in_sizes, int n_in,
                              void* d_out, int out_size, void* d_ws, size_t ws_size,
                              hipStream_t stream) {
  const float* in1 = (const float*)d_in[0];
  const float* in2 = (const float*)d_in[1];
  const float* in3 = (const float*)d_in[2];
  float* out = (float*)d_out;

  dim3 grid(WW / XCH, HH / YSTRIP, NB);
  sepconv_mfma<<<grid, NTHREADS, 0, stream>>>(in1, in2, in3, out);
}